// Round 2
// baseline (593.735 us; speedup 1.0000x reference)
//
#include <hip/hip_runtime.h>
#include <stdint.h>
#include <math.h>

// ---------------------------------------------------------------------------
// MultiHeadAttention: B=4, S=2048, D=1024, H=16, dk=64
// Raw-reshape head split: head (b,h) = rows [b*2048+h*128, +128) of the
// projected [8192][1024] matrix, reinterpreted as [2048][64].
// R1: barrier-free attention. S^T via mfma(K,Q) so P^T's C-layout == the
// B-fragment layout of mfma_f32_16x16x16f16 -> PV directly from registers.
// No LDS, no __syncthreads, 2 shuffles per 64-key tile for softmax.
// ---------------------------------------------------------------------------

typedef __attribute__((ext_vector_type(8))) short short8;
typedef __attribute__((ext_vector_type(4))) float f32x4;
typedef __attribute__((ext_vector_type(4))) unsigned int u32x4;
typedef __attribute__((ext_vector_type(4))) _Float16 half4;

__device__ __forceinline__ unsigned short bf16rne(float f) {
  unsigned int u = __builtin_bit_cast(unsigned int, f);
  unsigned int r = u + 0x7FFFu + ((u >> 16) & 1u);
  return (unsigned short)(r >> 16);
}

// async global->LDS, 16B per lane. LDS dest must be wave-uniform base + lane*16.
__device__ __forceinline__ void gld_lds16(const void* g, void* l) {
  typedef __attribute__((address_space(3))) unsigned int lds_u32;
  typedef const __attribute__((address_space(1))) unsigned int glb_u32;
  __builtin_amdgcn_global_load_lds((glb_u32*)(uintptr_t)g,
                                   (lds_u32*)(unsigned int)(uintptr_t)l,
                                   16, 0, 0);
}

// ---------------------------------------------------------------------------
// fp32 -> bf16 convert for Q,K,V   (3 x 8192 x 1024)
// ---------------------------------------------------------------------------
__global__ void convert_x_kernel(const float* __restrict__ Q,
                                 const float* __restrict__ K,
                                 const float* __restrict__ V,
                                 unsigned short* __restrict__ Xb) {
  const int z = blockIdx.y;
  const float* src = (z == 0) ? Q : (z == 1) ? K : V;
  const size_t i0 = ((size_t)blockIdx.x * 256 + threadIdx.x) * 8;
  const f32x4 a = *(const f32x4*)(src + i0);
  const f32x4 c = *(const f32x4*)(src + i0 + 4);
  u32x4 o;
  o[0] = (unsigned)bf16rne(a[0]) | ((unsigned)bf16rne(a[1]) << 16);
  o[1] = (unsigned)bf16rne(a[2]) | ((unsigned)bf16rne(a[3]) << 16);
  o[2] = (unsigned)bf16rne(c[0]) | ((unsigned)bf16rne(c[1]) << 16);
  o[3] = (unsigned)bf16rne(c[2]) | ((unsigned)bf16rne(c[3]) << 16);
  *(u32x4*)(Xb + (size_t)z * 8388608 + i0) = o;
}

// ---------------------------------------------------------------------------
// W [K=1024][N=1024] fp32 -> Wt [N][K] bf16 (transposed so GEMMs are A*B^T)
// ---------------------------------------------------------------------------
__global__ void convert_w_kernel(const float* __restrict__ W0,
                                 const float* __restrict__ W1,
                                 const float* __restrict__ W2,
                                 const float* __restrict__ W3,
                                 unsigned short* __restrict__ Wt) {
  const int z = blockIdx.z;
  const float* W = (z == 0) ? W0 : (z == 1) ? W1 : (z == 2) ? W2 : W3;
  unsigned short* dst = Wt + (size_t)z * 1048576;
  __shared__ float tile[32][33];
  const int tx = threadIdx.x & 31, ty = threadIdx.x >> 5;
  const int k0 = blockIdx.x * 32, n0 = blockIdx.y * 32;
#pragma unroll
  for (int yy = 0; yy < 32; yy += 8)
    tile[ty + yy][tx] = W[(size_t)(k0 + ty + yy) * 1024 + n0 + tx];
  __syncthreads();
#pragma unroll
  for (int yy = 0; yy < 32; yy += 8)
    dst[(size_t)(n0 + ty + yy) * 1024 + k0 + tx] = bf16rne(tile[tx][ty + yy]);
}

// ---------------------------------------------------------------------------
// GEMM (m97 structure): C[z] = A[z][8192x1024] * Bt[z][1024x1024]^T
// ---------------------------------------------------------------------------
__global__ __launch_bounds__(256, 2) void gemm_bt_kernel(
    const unsigned short* __restrict__ A, const unsigned short* __restrict__ Bt,
    unsigned short* __restrict__ Cbf, float* __restrict__ Cf32, float scaleZ0) {
  constexpr int K = 1024, N = 1024;
  const int z = blockIdx.z;
  const unsigned short* Ab = A + (size_t)z * 8192 * 1024;
  const unsigned short* Bb = Bt + (size_t)z * 1024 * 1024;
  const int tid = threadIdx.x;
  const int lane = tid & 63;
  const int w = tid >> 6;
  const int l15 = lane & 15, quad = lane >> 4;
  const int rowBase = blockIdx.x * 128;
  const int colBase = blockIdx.y * 128;
  const int wrow = (w >> 1) * 64;
  const int wcol = (w & 1) * 64;
  __shared__ __align__(16) unsigned short As[128 * 32];
  __shared__ __align__(16) unsigned short Bs[128 * 32];

  const f32x4 z4 = {0.0f, 0.0f, 0.0f, 0.0f};
  f32x4 acc[4][4];
#pragma unroll
  for (int i = 0; i < 4; i++)
#pragma unroll
    for (int j = 0; j < 4; j++) acc[i][j] = z4;

  const int s0 = tid, s1 = tid + 256;
  const int rA0 = s0 >> 2, cA0 = (s0 & 3) * 8;
  const int rA1 = s1 >> 2, cA1 = (s1 & 3) * 8;

  for (int k0 = 0; k0 < K; k0 += 32) {
    gld_lds16(Ab + (size_t)(rowBase + rA0) * K + k0 + cA0, (void*)(As + s0 * 8));
    gld_lds16(Ab + (size_t)(rowBase + rA1) * K + k0 + cA1, (void*)(As + s1 * 8));
    gld_lds16(Bb + (size_t)(colBase + rA0) * K + k0 + cA0, (void*)(Bs + s0 * 8));
    gld_lds16(Bb + (size_t)(colBase + rA1) * K + k0 + cA1, (void*)(Bs + s1 * 8));
    __syncthreads();
    short8 af[4], bfr[4];
#pragma unroll
    for (int i = 0; i < 4; i++)
      af[i] = *(const short8*)(As + (wrow + i * 16 + l15) * 32 + quad * 8);
#pragma unroll
    for (int j = 0; j < 4; j++)
      bfr[j] = *(const short8*)(Bs + (wcol + j * 16 + l15) * 32 + quad * 8);
#pragma unroll
    for (int i = 0; i < 4; i++)
#pragma unroll
      for (int j = 0; j < 4; j++)
        acc[i][j] =
            __builtin_amdgcn_mfma_f32_16x16x32_bf16(af[i], bfr[j], acc[i][j], 0, 0, 0);
    __syncthreads();
  }

  const float sc = (z == 0) ? scaleZ0 : 1.0f;
#pragma unroll
  for (int i = 0; i < 4; i++) {
#pragma unroll
    for (int j = 0; j < 4; j++) {
#pragma unroll
      for (int r = 0; r < 4; r++) {
        const int row = rowBase + wrow + i * 16 + quad * 4 + r;
        const int col = colBase + wcol + j * 16 + l15;
        const float v = acc[i][j][r] * sc;
        if (Cbf != nullptr) {
          Cbf[(size_t)z * 8192 * 1024 + (size_t)row * N + col] = bf16rne(v);
        } else {
          Cf32[(size_t)row * N + col] = v;
        }
      }
    }
  }
}

// ---------------------------------------------------------------------------
// V transpose: lin_v head (b,h) [2048][64] bf16 -> Vt[bh][64][2048] f16.
// Grid (16 s-tiles, 64 heads), block 256. Tiny (16 MB).
// ---------------------------------------------------------------------------
__global__ void vtrans_kernel(const unsigned short* __restrict__ linv,
                              unsigned short* __restrict__ Vt) {
  const int st = blockIdx.x, bh = blockIdx.y;
  const unsigned short* vp = linv + (size_t)bh * 131072;
  __shared__ unsigned short tile[64 * 136];
  const int tid = threadIdx.x;
#pragma unroll
  for (int it = 0; it < 4; it++) {
    const int idx = it * 256 + tid;        // 0..1023
    const int s = idx >> 3, d0 = (idx & 7) * 8;
    const u32x4 vv = *(const u32x4*)(vp + (size_t)(st * 128 + s) * 64 + d0);
#pragma unroll
    for (int m = 0; m < 4; m++) {
      const unsigned lo = vv[m] & 0xffffu, hi = vv[m] >> 16;
      const float f0 = __builtin_bit_cast(float, lo << 16);
      const float f1 = __builtin_bit_cast(float, hi << 16);
      const _Float16 h0 = (_Float16)f0, h1 = (_Float16)f1;
      tile[(d0 + 2 * m) * 136 + s] = __builtin_bit_cast(unsigned short, h0);
      tile[(d0 + 2 * m + 1) * 136 + s] = __builtin_bit_cast(unsigned short, h1);
    }
  }
  __syncthreads();
#pragma unroll
  for (int it = 0; it < 4; it++) {
    const int idx = it * 256 + tid;
    const int d = idx >> 4, s0 = (idx & 15) * 8;
    const u32x4 o = *(const u32x4*)(tile + d * 136 + s0);
    *(u32x4*)(Vt + (size_t)bh * 131072 + (size_t)d * 2048 + st * 128 + s0) = o;
  }
}

// ---------------------------------------------------------------------------
// Barrier-free flash attention. Grid (16 q-tiles, 64 b*h), block 256 (4 waves).
// Wave w: q-rows [qt*128+w*32, +32). Per 64-key tile:
//   S^T = mfma_bf16_K32(K_frag, Q_frag)  -> C-layout: lane holds key=quad*4+r,
//                                           col q = l15  (== f16 B-frag layout!)
//   softmax per-lane (q on l15), 2 shuffles per q-tile
//   P^T (f16, in regs) feeds mfma_f32_16x16x16f16(V^T_frag, P_frag) directly.
// Zero LDS, zero barriers. Q pre-scaled by 0.125*log2e (exp2-domain softmax).
// ---------------------------------------------------------------------------
__global__ __launch_bounds__(256, 4) void attn_kernel(
    const unsigned short* __restrict__ lin, const _Float16* __restrict__ Vt,
    unsigned short* __restrict__ ctxr) {
  const int qt = blockIdx.x;
  const int bh = blockIdx.y;
  const int b = bh >> 4, h = bh & 15;
  const int tid = threadIdx.x, lane = tid & 63, w = tid >> 6;
  const int l15 = lane & 15, quad = lane >> 4;
  const size_t headOff = (size_t)(b * 2048 + h * 128) * 1024;
  const unsigned short* qp = lin + headOff;
  const unsigned short* kp = lin + 8388608 + headOff;
  const _Float16* vtp = Vt + (size_t)bh * 131072;

  // Q as B-fragments (q on l15), held for the whole kernel.
  const int qrow0 = qt * 128 + w * 32;
  short8 bq[2][2];
#pragma unroll
  for (int i2 = 0; i2 < 2; i2++)
#pragma unroll
    for (int kk = 0; kk < 2; kk++)
      bq[i2][kk] = *(const short8*)(qp + (size_t)(qrow0 + i2 * 16 + l15) * 64 +
                                    kk * 32 + quad * 8);

  const f32x4 z4 = {0.0f, 0.0f, 0.0f, 0.0f};
  f32x4 co[4][2];  // ctx^T: rows d = dtile*16+quad*4+r, cols q = i2*16+l15
#pragma unroll
  for (int dt = 0; dt < 4; dt++)
#pragma unroll
    for (int i2 = 0; i2 < 2; i2++) co[dt][i2] = z4;
  float mrun[2] = {-INFINITY, -INFINITY};
  float lrun[2] = {0.0f, 0.0f};

  for (int kt = 0; kt < 32; kt++) {  // 64 keys per iteration
    const int key0 = kt * 64;
    // ---- S^T tiles
    f32x4 sacc[2][4];
#pragma unroll
    for (int ktile = 0; ktile < 4; ktile++) {
      const unsigned short* kb =
          kp + (size_t)(key0 + ktile * 16 + l15) * 64 + quad * 8;
      const short8 kf0 = *(const short8*)(kb);
      const short8 kf1 = *(const short8*)(kb + 32);
#pragma unroll
      for (int i2 = 0; i2 < 2; i2++) {
        f32x4 t = __builtin_amdgcn_mfma_f32_16x16x32_bf16(kf0, bq[i2][0], z4, 0, 0, 0);
        sacc[i2][ktile] =
            __builtin_amdgcn_mfma_f32_16x16x32_bf16(kf1, bq[i2][1], t, 0, 0, 0);
      }
    }
    // ---- online softmax (each lane owns q = i2*16+l15; keys split over quads)
    half4 pb[2][4];
    float alpha[2];
#pragma unroll
    for (int i2 = 0; i2 < 2; i2++) {
      float mx = sacc[i2][0][0];
#pragma unroll
      for (int t4 = 0; t4 < 4; t4++)
#pragma unroll
        for (int r = 0; r < 4; r++) mx = fmaxf(mx, sacc[i2][t4][r]);
      mx = fmaxf(mx, __shfl_xor(mx, 16, 64));
      mx = fmaxf(mx, __shfl_xor(mx, 32, 64));
      const float mnew = fmaxf(mrun[i2], mx);
      const float a = exp2f(mrun[i2] - mnew);
      float ls = 0.0f;
#pragma unroll
      for (int t4 = 0; t4 < 4; t4++) {
#pragma unroll
        for (int r = 0; r < 4; r++) {
          const float p = exp2f(sacc[i2][t4][r] - mnew);
          sacc[i2][t4][r] = p;
          ls += p;
        }
      }
      ls += __shfl_xor(ls, 16, 64);
      ls += __shfl_xor(ls, 32, 64);
      lrun[i2] = lrun[i2] * a + ls;
      mrun[i2] = mnew;
      alpha[i2] = a;
#pragma unroll
      for (int t4 = 0; t4 < 4; t4++) {
        half4 ph;
        ph[0] = (_Float16)sacc[i2][t4][0];
        ph[1] = (_Float16)sacc[i2][t4][1];
        ph[2] = (_Float16)sacc[i2][t4][2];
        ph[3] = (_Float16)sacc[i2][t4][3];
        pb[i2][t4] = ph;
      }
    }
#pragma unroll
    for (int dt = 0; dt < 4; dt++)
#pragma unroll
      for (int i2 = 0; i2 < 2; i2++) co[dt][i2] *= alpha[i2];
    // ---- O^T += V^T P^T   (P straight from registers)
#pragma unroll
    for (int ks = 0; ks < 4; ks++) {
#pragma unroll
      for (int dt = 0; dt < 4; dt++) {
        const half4 vf = *(const half4*)(vtp + (size_t)(dt * 16 + l15) * 2048 +
                                         key0 + ks * 16 + quad * 4);
#pragma unroll
        for (int i2 = 0; i2 < 2; i2++)
          co[dt][i2] =
              __builtin_amdgcn_mfma_f32_16x16x16f16(vf, pb[i2][ks], co[dt][i2], 0, 0, 0);
      }
    }
  }

  // ---- epilogue: ctxr[b*2048 + q][h*64 + d] = co^T / l
#pragma unroll
  for (int i2 = 0; i2 < 2; i2++) {
    const float inv = 1.0f / lrun[i2];
    const int srow = qrow0 + i2 * 16 + l15;
#pragma unroll
    for (int dt = 0; dt < 4; dt++) {
#pragma unroll
      for (int r = 0; r < 4; r++) {
        const int col = h * 64 + dt * 16 + quad * 4 + r;
        ctxr[(size_t)(b * 2048 + srow) * 1024 + col] = bf16rne(co[dt][i2][r] * inv);
      }
    }
  }
}

// ---------------------------------------------------------------------------
extern "C" void kernel_launch(void* const* d_in, const int* in_sizes, int n_in,
                              void* d_out, int out_size, void* d_ws, size_t ws_size,
                              hipStream_t stream) {
  const float* Q = (const float*)d_in[0];
  const float* K = (const float*)d_in[1];
  const float* V = (const float*)d_in[2];
  const float* WQ = (const float*)d_in[3];
  const float* WK = (const float*)d_in[4];
  const float* WV = (const float*)d_in[5];
  const float* Wfc = (const float*)d_in[6];
  float* out = (float*)d_out;

  unsigned short* ws = (unsigned short*)d_ws;
  // ws layout (ushort units):
  //   Xb   @ 0         : 3*8388608  (bf16 Q,K,V)      [dead after projections]
  //   ctxr @ 0         : 8388608    (bf16 ctx)        [overlays Xb]
  //   Vt   @ 8388608   : 8388608    (f16 V^T)         [overlays Xb]
  //   Wt   @ 25165824  : 4*1048576  (bf16 W^T: q,k,v,fc)
  //   lin  @ 29360128  : 3*8388608  (bf16 projections)
  unsigned short* Xb = ws;
  unsigned short* ctxr = ws;
  unsigned short* Vt = ws + 8388608;
  unsigned short* Wt = ws + 25165824;
  unsigned short* lin = ws + 29360128;

  convert_x_kernel<<<dim3(4096, 3), 256, 0, stream>>>(Q, K, V, Xb);
  convert_w_kernel<<<dim3(32, 32, 4), 256, 0, stream>>>(WQ, WK, WV, Wfc, Wt);
  const float qscale = 0.125f * 1.4426950408889634f;  // 1/sqrt(dk) * log2(e)
  gemm_bt_kernel<<<dim3(64, 8, 3), 256, 0, stream>>>(Xb, Wt, lin, nullptr, qscale);
  vtrans_kernel<<<dim3(16, 64), 256, 0, stream>>>(lin + 16777216, Vt);
  attn_kernel<<<dim3(16, 64), 256, 0, stream>>>(lin, (const _Float16*)Vt, ctxr);
  gemm_bt_kernel<<<dim3(64, 8, 1), 256, 0, stream>>>(ctxr, Wt + 3 * 1048576, nullptr,
                                                     out, 1.0f);
}

// Round 3
// 590.090 us; speedup vs baseline: 1.0062x; 1.0062x over previous
//
#include <hip/hip_runtime.h>
#include <stdint.h>
#include <math.h>

// ---------------------------------------------------------------------------
// MultiHeadAttention: B=4, S=2048, D=1024, H=16, dk=64
// Raw-reshape head split: head (b,h) = rows [b*2048+h*128, +128) of the
// projected [8192][1024] matrix, reinterpreted as [2048][64].
// R2: barrier-free attention + register software-pipeline:
//   - K fragments double-buffered in VGPRs (prefetch tile kt+1 during kt)
//   - V loads issued at body top, consumed ~300cyc later at PV
//   - grid (bh, qt) so one head's blocks share an XCD -> K/V L2-resident
// S^T via mfma(K,Q): P^T C-layout == B-frag layout of mfma_f32_16x16x16f16,
// so PV runs straight from registers. No LDS, no barriers.
// ---------------------------------------------------------------------------

typedef __attribute__((ext_vector_type(8))) short short8;
typedef __attribute__((ext_vector_type(4))) float f32x4;
typedef __attribute__((ext_vector_type(4))) unsigned int u32x4;
typedef __attribute__((ext_vector_type(4))) _Float16 half4;

__device__ __forceinline__ unsigned short bf16rne(float f) {
  unsigned int u = __builtin_bit_cast(unsigned int, f);
  unsigned int r = u + 0x7FFFu + ((u >> 16) & 1u);
  return (unsigned short)(r >> 16);
}

// async global->LDS, 16B per lane. LDS dest must be wave-uniform base + lane*16.
__device__ __forceinline__ void gld_lds16(const void* g, void* l) {
  typedef __attribute__((address_space(3))) unsigned int lds_u32;
  typedef const __attribute__((address_space(1))) unsigned int glb_u32;
  __builtin_amdgcn_global_load_lds((glb_u32*)(uintptr_t)g,
                                   (lds_u32*)(unsigned int)(uintptr_t)l,
                                   16, 0, 0);
}

// ---------------------------------------------------------------------------
// fp32 -> bf16 convert for Q,K,V   (3 x 8192 x 1024)
// ---------------------------------------------------------------------------
__global__ void convert_x_kernel(const float* __restrict__ Q,
                                 const float* __restrict__ K,
                                 const float* __restrict__ V,
                                 unsigned short* __restrict__ Xb) {
  const int z = blockIdx.y;
  const float* src = (z == 0) ? Q : (z == 1) ? K : V;
  const size_t i0 = ((size_t)blockIdx.x * 256 + threadIdx.x) * 8;
  const f32x4 a = *(const f32x4*)(src + i0);
  const f32x4 c = *(const f32x4*)(src + i0 + 4);
  u32x4 o;
  o[0] = (unsigned)bf16rne(a[0]) | ((unsigned)bf16rne(a[1]) << 16);
  o[1] = (unsigned)bf16rne(a[2]) | ((unsigned)bf16rne(a[3]) << 16);
  o[2] = (unsigned)bf16rne(c[0]) | ((unsigned)bf16rne(c[1]) << 16);
  o[3] = (unsigned)bf16rne(c[2]) | ((unsigned)bf16rne(c[3]) << 16);
  *(u32x4*)(Xb + (size_t)z * 8388608 + i0) = o;
}

// ---------------------------------------------------------------------------
// W [K=1024][N=1024] fp32 -> Wt [N][K] bf16 (transposed so GEMMs are A*B^T)
// ---------------------------------------------------------------------------
__global__ void convert_w_kernel(const float* __restrict__ W0,
                                 const float* __restrict__ W1,
                                 const float* __restrict__ W2,
                                 const float* __restrict__ W3,
                                 unsigned short* __restrict__ Wt) {
  const int z = blockIdx.z;
  const float* W = (z == 0) ? W0 : (z == 1) ? W1 : (z == 2) ? W2 : W3;
  unsigned short* dst = Wt + (size_t)z * 1048576;
  __shared__ float tile[32][33];
  const int tx = threadIdx.x & 31, ty = threadIdx.x >> 5;
  const int k0 = blockIdx.x * 32, n0 = blockIdx.y * 32;
#pragma unroll
  for (int yy = 0; yy < 32; yy += 8)
    tile[ty + yy][tx] = W[(size_t)(k0 + ty + yy) * 1024 + n0 + tx];
  __syncthreads();
#pragma unroll
  for (int yy = 0; yy < 32; yy += 8)
    dst[(size_t)(n0 + ty + yy) * 1024 + k0 + tx] = bf16rne(tile[tx][ty + yy]);
}

// ---------------------------------------------------------------------------
// GEMM (m97 structure): C[z] = A[z][8192x1024] * Bt[z][1024x1024]^T
// ---------------------------------------------------------------------------
__global__ __launch_bounds__(256, 2) void gemm_bt_kernel(
    const unsigned short* __restrict__ A, const unsigned short* __restrict__ Bt,
    unsigned short* __restrict__ Cbf, float* __restrict__ Cf32, float scaleZ0) {
  constexpr int K = 1024, N = 1024;
  const int z = blockIdx.z;
  const unsigned short* Ab = A + (size_t)z * 8192 * 1024;
  const unsigned short* Bb = Bt + (size_t)z * 1024 * 1024;
  const int tid = threadIdx.x;
  const int lane = tid & 63;
  const int w = tid >> 6;
  const int l15 = lane & 15, quad = lane >> 4;
  const int rowBase = blockIdx.x * 128;
  const int colBase = blockIdx.y * 128;
  const int wrow = (w >> 1) * 64;
  const int wcol = (w & 1) * 64;
  __shared__ __align__(16) unsigned short As[128 * 32];
  __shared__ __align__(16) unsigned short Bs[128 * 32];

  const f32x4 z4 = {0.0f, 0.0f, 0.0f, 0.0f};
  f32x4 acc[4][4];
#pragma unroll
  for (int i = 0; i < 4; i++)
#pragma unroll
    for (int j = 0; j < 4; j++) acc[i][j] = z4;

  const int s0 = tid, s1 = tid + 256;
  const int rA0 = s0 >> 2, cA0 = (s0 & 3) * 8;
  const int rA1 = s1 >> 2, cA1 = (s1 & 3) * 8;

  for (int k0 = 0; k0 < K; k0 += 32) {
    gld_lds16(Ab + (size_t)(rowBase + rA0) * K + k0 + cA0, (void*)(As + s0 * 8));
    gld_lds16(Ab + (size_t)(rowBase + rA1) * K + k0 + cA1, (void*)(As + s1 * 8));
    gld_lds16(Bb + (size_t)(colBase + rA0) * K + k0 + cA0, (void*)(Bs + s0 * 8));
    gld_lds16(Bb + (size_t)(colBase + rA1) * K + k0 + cA1, (void*)(Bs + s1 * 8));
    __syncthreads();
    short8 af[4], bfr[4];
#pragma unroll
    for (int i = 0; i < 4; i++)
      af[i] = *(const short8*)(As + (wrow + i * 16 + l15) * 32 + quad * 8);
#pragma unroll
    for (int j = 0; j < 4; j++)
      bfr[j] = *(const short8*)(Bs + (wcol + j * 16 + l15) * 32 + quad * 8);
#pragma unroll
    for (int i = 0; i < 4; i++)
#pragma unroll
      for (int j = 0; j < 4; j++)
        acc[i][j] =
            __builtin_amdgcn_mfma_f32_16x16x32_bf16(af[i], bfr[j], acc[i][j], 0, 0, 0);
    __syncthreads();
  }

  const float sc = (z == 0) ? scaleZ0 : 1.0f;
#pragma unroll
  for (int i = 0; i < 4; i++) {
#pragma unroll
    for (int j = 0; j < 4; j++) {
#pragma unroll
      for (int r = 0; r < 4; r++) {
        const int row = rowBase + wrow + i * 16 + quad * 4 + r;
        const int col = colBase + wcol + j * 16 + l15;
        const float v = acc[i][j][r] * sc;
        if (Cbf != nullptr) {
          Cbf[(size_t)z * 8192 * 1024 + (size_t)row * N + col] = bf16rne(v);
        } else {
          Cf32[(size_t)row * N + col] = v;
        }
      }
    }
  }
}

// ---------------------------------------------------------------------------
// V transpose: lin_v head (b,h) [2048][64] bf16 -> Vt[bh][64][2048] f16.
// ---------------------------------------------------------------------------
__global__ void vtrans_kernel(const unsigned short* __restrict__ linv,
                              unsigned short* __restrict__ Vt) {
  const int st = blockIdx.x, bh = blockIdx.y;
  const unsigned short* vp = linv + (size_t)bh * 131072;
  __shared__ unsigned short tile[64 * 136];
  const int tid = threadIdx.x;
#pragma unroll
  for (int it = 0; it < 4; it++) {
    const int idx = it * 256 + tid;        // 0..1023
    const int s = idx >> 3, d0 = (idx & 7) * 8;
    const u32x4 vv = *(const u32x4*)(vp + (size_t)(st * 128 + s) * 64 + d0);
#pragma unroll
    for (int m = 0; m < 4; m++) {
      const unsigned lo = vv[m] & 0xffffu, hi = vv[m] >> 16;
      const float f0 = __builtin_bit_cast(float, lo << 16);
      const float f1 = __builtin_bit_cast(float, hi << 16);
      const _Float16 h0 = (_Float16)f0, h1 = (_Float16)f1;
      tile[(d0 + 2 * m) * 136 + s] = __builtin_bit_cast(unsigned short, h0);
      tile[(d0 + 2 * m + 1) * 136 + s] = __builtin_bit_cast(unsigned short, h1);
    }
  }
  __syncthreads();
#pragma unroll
  for (int it = 0; it < 4; it++) {
    const int idx = it * 256 + tid;
    const int d = idx >> 4, s0 = (idx & 15) * 8;
    const u32x4 o = *(const u32x4*)(tile + d * 136 + s0);
    *(u32x4*)(Vt + (size_t)bh * 131072 + (size_t)d * 2048 + st * 128 + s0) = o;
  }
}

// ---------------------------------------------------------------------------
// Barrier-free flash attention, register-pipelined.
// Grid (bh=64, qt=16) -> all blocks of one head share an XCD (L2-resident K/V).
// Block 256 = 4 waves; wave w owns q-rows [qt*128+w*32, +32).
// Per 64-key tile: V loads issued at body top; K for NEXT tile prefetched into
// the alternate register buffer; S^T = mfma_bf16(K,Q); per-lane softmax (2
// shuffles); P^T(f16) feeds mfma_f32_16x16x16f16 directly from registers.
// ---------------------------------------------------------------------------
__global__ __launch_bounds__(256, 2) void attn_kernel(
    const unsigned short* __restrict__ lin, const _Float16* __restrict__ Vt,
    unsigned short* __restrict__ ctxr) {
  const int bh = blockIdx.x;
  const int qt = blockIdx.y;
  const int b = bh >> 4, h = bh & 15;
  const int tid = threadIdx.x, lane = tid & 63, w = tid >> 6;
  const int l15 = lane & 15, quad = lane >> 4;
  const size_t headOff = (size_t)(b * 2048 + h * 128) * 1024;
  const unsigned short* qp = lin + headOff;
  const unsigned short* kp = lin + 8388608 + headOff;
  const _Float16* vtp = Vt + (size_t)bh * 131072;

  // Q as B-fragments (q on l15), held for the whole kernel.
  const int qrow0 = qt * 128 + w * 32;
  short8 bq[2][2];
#pragma unroll
  for (int i2 = 0; i2 < 2; i2++)
#pragma unroll
    for (int kk = 0; kk < 2; kk++)
      bq[i2][kk] = *(const short8*)(qp + (size_t)(qrow0 + i2 * 16 + l15) * 64 +
                                    kk * 32 + quad * 8);

  const f32x4 z4 = {0.0f, 0.0f, 0.0f, 0.0f};
  f32x4 co[4][2];  // ctx^T: rows d = dt*16+quad*4+r, cols q = i2*16+l15
#pragma unroll
  for (int dt = 0; dt < 4; dt++)
#pragma unroll
    for (int i2 = 0; i2 < 2; i2++) co[dt][i2] = z4;
  float mrun[2] = {-INFINITY, -INFINITY};
  float lrun[2] = {0.0f, 0.0f};

  // K register double-buffer; preload tile 0.
  short8 kfA[4][2], kfB[4][2];
#pragma unroll
  for (int t4 = 0; t4 < 4; t4++) {
    const unsigned short* kb = kp + (size_t)(t4 * 16 + l15) * 64 + quad * 8;
    kfA[t4][0] = *(const short8*)(kb);
    kfA[t4][1] = *(const short8*)(kb + 32);
  }

  auto step = [&](short8(&kcur)[4][2], short8(&knxt)[4][2], int kt) {
    const int key0 = kt * 64;
    // ---- V loads for this tile (consumed at PV, ~300cyc later)
    half4 vf[4][4];  // [ks][dt]
#pragma unroll
    for (int ks = 0; ks < 4; ks++)
#pragma unroll
      for (int dt = 0; dt < 4; dt++)
        vf[ks][dt] = *(const half4*)(vtp + (size_t)(dt * 16 + l15) * 2048 +
                                     key0 + ks * 16 + quad * 4);
    // ---- K prefetch for next tile
    if (kt < 31) {
#pragma unroll
      for (int t4 = 0; t4 < 4; t4++) {
        const unsigned short* kb =
            kp + (size_t)(key0 + 64 + t4 * 16 + l15) * 64 + quad * 8;
        knxt[t4][0] = *(const short8*)(kb);
        knxt[t4][1] = *(const short8*)(kb + 32);
      }
    }
    // ---- S^T tiles (K ready from previous iteration's prefetch)
    f32x4 sacc[2][4];
#pragma unroll
    for (int t4 = 0; t4 < 4; t4++) {
#pragma unroll
      for (int i2 = 0; i2 < 2; i2++) {
        f32x4 t =
            __builtin_amdgcn_mfma_f32_16x16x32_bf16(kcur[t4][0], bq[i2][0], z4, 0, 0, 0);
        sacc[i2][t4] =
            __builtin_amdgcn_mfma_f32_16x16x32_bf16(kcur[t4][1], bq[i2][1], t, 0, 0, 0);
      }
    }
    // ---- online softmax (lane owns q = i2*16+l15; keys split over quads)
    half4 pb[2][4];
    float alpha[2];
#pragma unroll
    for (int i2 = 0; i2 < 2; i2++) {
      float mx = sacc[i2][0][0];
#pragma unroll
      for (int t4 = 0; t4 < 4; t4++)
#pragma unroll
        for (int r = 0; r < 4; r++) mx = fmaxf(mx, sacc[i2][t4][r]);
      mx = fmaxf(mx, __shfl_xor(mx, 16, 64));
      mx = fmaxf(mx, __shfl_xor(mx, 32, 64));
      const float mnew = fmaxf(mrun[i2], mx);
      const float a = exp2f(mrun[i2] - mnew);
      float ls = 0.0f;
#pragma unroll
      for (int t4 = 0; t4 < 4; t4++) {
#pragma unroll
        for (int r = 0; r < 4; r++) {
          const float p = exp2f(sacc[i2][t4][r] - mnew);
          sacc[i2][t4][r] = p;
          ls += p;
        }
      }
      ls += __shfl_xor(ls, 16, 64);
      ls += __shfl_xor(ls, 32, 64);
      lrun[i2] = lrun[i2] * a + ls;
      mrun[i2] = mnew;
      alpha[i2] = a;
#pragma unroll
      for (int t4 = 0; t4 < 4; t4++) {
        half4 ph;
        ph[0] = (_Float16)sacc[i2][t4][0];
        ph[1] = (_Float16)sacc[i2][t4][1];
        ph[2] = (_Float16)sacc[i2][t4][2];
        ph[3] = (_Float16)sacc[i2][t4][3];
        pb[i2][t4] = ph;
      }
    }
#pragma unroll
    for (int dt = 0; dt < 4; dt++)
#pragma unroll
      for (int i2 = 0; i2 < 2; i2++) co[dt][i2] *= alpha[i2];
    // ---- O^T += V^T P^T  (both operands straight from registers)
#pragma unroll
    for (int ks = 0; ks < 4; ks++)
#pragma unroll
      for (int dt = 0; dt < 4; dt++)
#pragma unroll
        for (int i2 = 0; i2 < 2; i2++)
          co[dt][i2] = __builtin_amdgcn_mfma_f32_16x16x16f16(vf[ks][dt], pb[i2][ks],
                                                             co[dt][i2], 0, 0, 0);
  };

  for (int kt = 0; kt < 32; kt += 2) {
    step(kfA, kfB, kt);
    step(kfB, kfA, kt + 1);
  }

  // ---- epilogue: ctxr[b*2048 + q][h*64 + d] = co^T / l
#pragma unroll
  for (int i2 = 0; i2 < 2; i2++) {
    const float inv = 1.0f / lrun[i2];
    const int srow = qrow0 + i2 * 16 + l15;
#pragma unroll
    for (int dt = 0; dt < 4; dt++) {
#pragma unroll
      for (int r = 0; r < 4; r++) {
        const int col = h * 64 + dt * 16 + quad * 4 + r;
        ctxr[(size_t)(b * 2048 + srow) * 1024 + col] = bf16rne(co[dt][i2][r] * inv);
      }
    }
  }
}

// ---------------------------------------------------------------------------
extern "C" void kernel_launch(void* const* d_in, const int* in_sizes, int n_in,
                              void* d_out, int out_size, void* d_ws, size_t ws_size,
                              hipStream_t stream) {
  const float* Q = (const float*)d_in[0];
  const float* K = (const float*)d_in[1];
  const float* V = (const float*)d_in[2];
  const float* WQ = (const float*)d_in[3];
  const float* WK = (const float*)d_in[4];
  const float* WV = (const float*)d_in[5];
  const float* Wfc = (const float*)d_in[6];
  float* out = (float*)d_out;

  unsigned short* ws = (unsigned short*)d_ws;
  // ws layout (ushort units):
  //   Xb   @ 0         : 3*8388608  (bf16 Q,K,V)      [dead after projections]
  //   ctxr @ 0         : 8388608    (bf16 ctx)        [overlays Xb]
  //   Vt   @ 8388608   : 8388608    (f16 V^T)         [overlays Xb]
  //   Wt   @ 25165824  : 4*1048576  (bf16 W^T: q,k,v,fc)
  //   lin  @ 29360128  : 3*8388608  (bf16 projections)
  unsigned short* Xb = ws;
  unsigned short* ctxr = ws;
  unsigned short* Vt = ws + 8388608;
  unsigned short* Wt = ws + 25165824;
  unsigned short* lin = ws + 29360128;

  convert_x_kernel<<<dim3(4096, 3), 256, 0, stream>>>(Q, K, V, Xb);
  convert_w_kernel<<<dim3(32, 32, 4), 256, 0, stream>>>(WQ, WK, WV, Wfc, Wt);
  const float qscale = 0.125f * 1.4426950408889634f;  // 1/sqrt(dk) * log2(e)
  gemm_bt_kernel<<<dim3(64, 8, 3), 256, 0, stream>>>(Xb, Wt, lin, nullptr, qscale);
  vtrans_kernel<<<dim3(16, 64), 256, 0, stream>>>(lin + 16777216, Vt);
  attn_kernel<<<dim3(64, 16), 256, 0, stream>>>(lin, (const _Float16*)Vt, ctxr);
  gemm_bt_kernel<<<dim3(64, 8, 1), 256, 0, stream>>>(ctxr, Wt + 3 * 1048576, nullptr,
                                                     out, 1.0f);
}

// Round 4
// 439.700 us; speedup vs baseline: 1.3503x; 1.3420x over previous
//
#include <hip/hip_runtime.h>
#include <stdint.h>
#include <math.h>

// ---------------------------------------------------------------------------
// MultiHeadAttention: B=4, S=2048, D=1024, H=16, dk=64
// Raw-reshape head split: head (b,h) = rows [b*2048+h*128, +128) of the
// projected [8192][1024] matrix, reinterpreted as [2048][64].
// R3: attention with m97-style async double-buffered LDS staging of K and V
// (global_load_lds width 16 — side-effecting, so the compiler can't sink it,
// unlike R2's register prefetch which got rescheduled away: VGPR=96 < live
// estimate proved loads were re-sunk into the dependency chain).
// K/V staged ONCE per block (shared by 4 waves; R2 loaded them per-wave = 4x).
// XOR-swizzled LDS slots -> conflict-free ds_read_b128/b64 fragments.
// S^T = mfma(K,Q) so P^T C-layout == B-frag layout of mfma_f32_16x16x16f16:
// PV straight from registers. One barrier per 64-key tile.
// ---------------------------------------------------------------------------

typedef __attribute__((ext_vector_type(8))) short short8;
typedef __attribute__((ext_vector_type(4))) float f32x4;
typedef __attribute__((ext_vector_type(4))) unsigned int u32x4;
typedef __attribute__((ext_vector_type(4))) _Float16 half4;

__device__ __forceinline__ unsigned short bf16rne(float f) {
  unsigned int u = __builtin_bit_cast(unsigned int, f);
  unsigned int r = u + 0x7FFFu + ((u >> 16) & 1u);
  return (unsigned short)(r >> 16);
}

// async global->LDS, 16B per lane. LDS dest must be wave-uniform base + lane*16.
__device__ __forceinline__ void gld_lds16(const void* g, void* l) {
  typedef __attribute__((address_space(3))) unsigned int lds_u32;
  typedef const __attribute__((address_space(1))) unsigned int glb_u32;
  __builtin_amdgcn_global_load_lds((glb_u32*)(uintptr_t)g,
                                   (lds_u32*)(unsigned int)(uintptr_t)l,
                                   16, 0, 0);
}

// ---------------------------------------------------------------------------
// fp32 -> bf16 convert for Q,K,V   (3 x 8192 x 1024)
// ---------------------------------------------------------------------------
__global__ void convert_x_kernel(const float* __restrict__ Q,
                                 const float* __restrict__ K,
                                 const float* __restrict__ V,
                                 unsigned short* __restrict__ Xb) {
  const int z = blockIdx.y;
  const float* src = (z == 0) ? Q : (z == 1) ? K : V;
  const size_t i0 = ((size_t)blockIdx.x * 256 + threadIdx.x) * 8;
  const f32x4 a = *(const f32x4*)(src + i0);
  const f32x4 c = *(const f32x4*)(src + i0 + 4);
  u32x4 o;
  o[0] = (unsigned)bf16rne(a[0]) | ((unsigned)bf16rne(a[1]) << 16);
  o[1] = (unsigned)bf16rne(a[2]) | ((unsigned)bf16rne(a[3]) << 16);
  o[2] = (unsigned)bf16rne(c[0]) | ((unsigned)bf16rne(c[1]) << 16);
  o[3] = (unsigned)bf16rne(c[2]) | ((unsigned)bf16rne(c[3]) << 16);
  *(u32x4*)(Xb + (size_t)z * 8388608 + i0) = o;
}

// ---------------------------------------------------------------------------
// W [K=1024][N=1024] fp32 -> Wt [N][K] bf16 (transposed so GEMMs are A*B^T)
// ---------------------------------------------------------------------------
__global__ void convert_w_kernel(const float* __restrict__ W0,
                                 const float* __restrict__ W1,
                                 const float* __restrict__ W2,
                                 const float* __restrict__ W3,
                                 unsigned short* __restrict__ Wt) {
  const int z = blockIdx.z;
  const float* W = (z == 0) ? W0 : (z == 1) ? W1 : (z == 2) ? W2 : W3;
  unsigned short* dst = Wt + (size_t)z * 1048576;
  __shared__ float tile[32][33];
  const int tx = threadIdx.x & 31, ty = threadIdx.x >> 5;
  const int k0 = blockIdx.x * 32, n0 = blockIdx.y * 32;
#pragma unroll
  for (int yy = 0; yy < 32; yy += 8)
    tile[ty + yy][tx] = W[(size_t)(k0 + ty + yy) * 1024 + n0 + tx];
  __syncthreads();
#pragma unroll
  for (int yy = 0; yy < 32; yy += 8)
    dst[(size_t)(n0 + ty + yy) * 1024 + k0 + tx] = bf16rne(tile[tx][ty + yy]);
}

// ---------------------------------------------------------------------------
// GEMM (m97 structure): C[z] = A[z][8192x1024] * Bt[z][1024x1024]^T
// ---------------------------------------------------------------------------
__global__ __launch_bounds__(256, 2) void gemm_bt_kernel(
    const unsigned short* __restrict__ A, const unsigned short* __restrict__ Bt,
    unsigned short* __restrict__ Cbf, float* __restrict__ Cf32, float scaleZ0) {
  constexpr int K = 1024, N = 1024;
  const int z = blockIdx.z;
  const unsigned short* Ab = A + (size_t)z * 8192 * 1024;
  const unsigned short* Bb = Bt + (size_t)z * 1024 * 1024;
  const int tid = threadIdx.x;
  const int lane = tid & 63;
  const int w = tid >> 6;
  const int l15 = lane & 15, quad = lane >> 4;
  const int rowBase = blockIdx.x * 128;
  const int colBase = blockIdx.y * 128;
  const int wrow = (w >> 1) * 64;
  const int wcol = (w & 1) * 64;
  __shared__ __align__(16) unsigned short As[128 * 32];
  __shared__ __align__(16) unsigned short Bs[128 * 32];

  const f32x4 z4 = {0.0f, 0.0f, 0.0f, 0.0f};
  f32x4 acc[4][4];
#pragma unroll
  for (int i = 0; i < 4; i++)
#pragma unroll
    for (int j = 0; j < 4; j++) acc[i][j] = z4;

  const int s0 = tid, s1 = tid + 256;
  const int rA0 = s0 >> 2, cA0 = (s0 & 3) * 8;
  const int rA1 = s1 >> 2, cA1 = (s1 & 3) * 8;

  for (int k0 = 0; k0 < K; k0 += 32) {
    gld_lds16(Ab + (size_t)(rowBase + rA0) * K + k0 + cA0, (void*)(As + s0 * 8));
    gld_lds16(Ab + (size_t)(rowBase + rA1) * K + k0 + cA1, (void*)(As + s1 * 8));
    gld_lds16(Bb + (size_t)(colBase + rA0) * K + k0 + cA0, (void*)(Bs + s0 * 8));
    gld_lds16(Bb + (size_t)(colBase + rA1) * K + k0 + cA1, (void*)(Bs + s1 * 8));
    __syncthreads();
    short8 af[4], bfr[4];
#pragma unroll
    for (int i = 0; i < 4; i++)
      af[i] = *(const short8*)(As + (wrow + i * 16 + l15) * 32 + quad * 8);
#pragma unroll
    for (int j = 0; j < 4; j++)
      bfr[j] = *(const short8*)(Bs + (wcol + j * 16 + l15) * 32 + quad * 8);
#pragma unroll
    for (int i = 0; i < 4; i++)
#pragma unroll
      for (int j = 0; j < 4; j++)
        acc[i][j] =
            __builtin_amdgcn_mfma_f32_16x16x32_bf16(af[i], bfr[j], acc[i][j], 0, 0, 0);
    __syncthreads();
  }

  const float sc = (z == 0) ? scaleZ0 : 1.0f;
#pragma unroll
  for (int i = 0; i < 4; i++) {
#pragma unroll
    for (int j = 0; j < 4; j++) {
#pragma unroll
      for (int r = 0; r < 4; r++) {
        const int row = rowBase + wrow + i * 16 + quad * 4 + r;
        const int col = colBase + wcol + j * 16 + l15;
        const float v = acc[i][j][r] * sc;
        if (Cbf != nullptr) {
          Cbf[(size_t)z * 8192 * 1024 + (size_t)row * N + col] = bf16rne(v);
        } else {
          Cf32[(size_t)row * N + col] = v;
        }
      }
    }
  }
}

// ---------------------------------------------------------------------------
// V transpose: lin_v head (b,h) [2048][64] bf16 -> Vt[bh][64][2048] f16.
// ---------------------------------------------------------------------------
__global__ void vtrans_kernel(const unsigned short* __restrict__ linv,
                              unsigned short* __restrict__ Vt) {
  const int st = blockIdx.x, bh = blockIdx.y;
  const unsigned short* vp = linv + (size_t)bh * 131072;
  __shared__ unsigned short tile[64 * 136];
  const int tid = threadIdx.x;
#pragma unroll
  for (int it = 0; it < 4; it++) {
    const int idx = it * 256 + tid;        // 0..1023
    const int s = idx >> 3, d0 = (idx & 7) * 8;
    const u32x4 vv = *(const u32x4*)(vp + (size_t)(st * 128 + s) * 64 + d0);
#pragma unroll
    for (int m = 0; m < 4; m++) {
      const unsigned lo = vv[m] & 0xffffu, hi = vv[m] >> 16;
      const float f0 = __builtin_bit_cast(float, lo << 16);
      const float f1 = __builtin_bit_cast(float, hi << 16);
      const _Float16 h0 = (_Float16)f0, h1 = (_Float16)f1;
      tile[(d0 + 2 * m) * 136 + s] = __builtin_bit_cast(unsigned short, h0);
      tile[(d0 + 2 * m + 1) * 136 + s] = __builtin_bit_cast(unsigned short, h1);
    }
  }
  __syncthreads();
#pragma unroll
  for (int it = 0; it < 4; it++) {
    const int idx = it * 256 + tid;
    const int d = idx >> 4, s0 = (idx & 15) * 8;
    const u32x4 o = *(const u32x4*)(tile + d * 136 + s0);
    *(u32x4*)(Vt + (size_t)bh * 131072 + (size_t)d * 2048 + st * 128 + s0) = o;
  }
}

// ---------------------------------------------------------------------------
// Flash attention, async-LDS double-buffered.
// Grid (bh=64, qt=16) -> one head's blocks share an XCD (L2-resident K/V).
// Block 256 = 4 waves; wave w owns q-rows [qt*128+w*32, +32).
// LDS tiles (64 keys): Ks [key][dp] 8KB, Vs [d][kp] 8KB, double-buffered=32KB.
// Slot swizzle: dp = dseg ^ (key&7) (resp. kp = kseg ^ (d&7)) so fragment
// ds_reads spread across all bank groups (conflict-free).
// Per tile: stage(next) -> ds_read K -> S^T MFMA -> ds_read V -> softmax
// (hides V latency) -> PV from registers -> one barrier.
// ---------------------------------------------------------------------------
__global__ __launch_bounds__(256, 4) void attn_kernel(
    const unsigned short* __restrict__ lin, const _Float16* __restrict__ Vt,
    unsigned short* __restrict__ ctxr) {
  const int bh = blockIdx.x;
  const int qt = blockIdx.y;
  const int b = bh >> 4, h = bh & 15;
  const int tid = threadIdx.x, lane = tid & 63, w = tid >> 6;
  const int l15 = lane & 15, quad = lane >> 4;
  const size_t headOff = (size_t)(b * 2048 + h * 128) * 1024;
  const unsigned short* qp = lin + headOff;
  const unsigned short* kp = lin + 8388608 + headOff;
  const _Float16* vtp = Vt + (size_t)bh * 131072;

  __shared__ __align__(16) unsigned short Ks[2][4096];  // 8KB per buf
  __shared__ __align__(16) _Float16 Vs[2][4096];        // 8KB per buf

  // Staging geometry (per wave, 4 instrs of 64 lanes x 16B):
  // waves 0,1 stage K (512 slots); waves 2,3 stage V (512 slots).
  const int stageV = (w >= 2);
  const int wbase = (stageV ? (w - 2) : w) * 256 + lane;

  auto stage = [&](int bufn, int key0) {
#pragma unroll
    for (int i = 0; i < 4; i++) {
      const int slot = wbase + i * 64;
      const int row = slot >> 3;                 // key (K) or d (V)
      const int seg = (slot & 7) ^ (row & 7);    // un-swizzled segment
      if (!stageV) {
        gld_lds16(kp + (size_t)(key0 + row) * 64 + seg * 8,
                  (void*)(&Ks[bufn][slot * 8]));
      } else {
        gld_lds16(vtp + (size_t)row * 2048 + key0 + seg * 8,
                  (void*)(&Vs[bufn][slot * 8]));
      }
    }
  };

  // Q as B-fragments (q on l15), held for the whole kernel.
  const int qrow0 = qt * 128 + w * 32;
  short8 bq[2][2];
#pragma unroll
  for (int i2 = 0; i2 < 2; i2++)
#pragma unroll
    for (int kk = 0; kk < 2; kk++)
      bq[i2][kk] = *(const short8*)(qp + (size_t)(qrow0 + i2 * 16 + l15) * 64 +
                                    kk * 32 + quad * 8);

  const f32x4 z4 = {0.0f, 0.0f, 0.0f, 0.0f};
  f32x4 co[4][2];  // ctx^T: rows d = dt*16+quad*4+r, cols q = i2*16+l15
#pragma unroll
  for (int dt = 0; dt < 4; dt++)
#pragma unroll
    for (int i2 = 0; i2 < 2; i2++) co[dt][i2] = z4;
  float mrun[2] = {-INFINITY, -INFINITY};
  float lrun[2] = {0.0f, 0.0f};

  stage(0, 0);
  __syncthreads();

  for (int kt = 0; kt < 32; kt++) {
    const int cur = kt & 1;
    if (kt < 31) stage(cur ^ 1, (kt + 1) * 64);

    // ---- K fragments from LDS (swizzled slots; conflict-free b128)
    short8 kf[4][2];
#pragma unroll
    for (int t4 = 0; t4 < 4; t4++) {
      const int key = t4 * 16 + l15;
#pragma unroll
      for (int kk = 0; kk < 2; kk++) {
        const int slot = key * 8 + ((kk * 4 + quad) ^ (key & 7));
        kf[t4][kk] = *(const short8*)(&Ks[cur][slot * 8]);
      }
    }
    // ---- S^T tiles
    f32x4 sacc[2][4];
#pragma unroll
    for (int t4 = 0; t4 < 4; t4++) {
#pragma unroll
      for (int i2 = 0; i2 < 2; i2++) {
        f32x4 t =
            __builtin_amdgcn_mfma_f32_16x16x32_bf16(kf[t4][0], bq[i2][0], z4, 0, 0, 0);
        sacc[i2][t4] =
            __builtin_amdgcn_mfma_f32_16x16x32_bf16(kf[t4][1], bq[i2][1], t, 0, 0, 0);
      }
    }
    // ---- V fragments from LDS (b64; latency hides under softmax VALU)
    half4 vf[4][4];  // [ks][dt]
#pragma unroll
    for (int ks = 0; ks < 4; ks++) {
#pragma unroll
      for (int dt = 0; dt < 4; dt++) {
        const int d = dt * 16 + l15;
        const int kseg = ks * 2 + (quad >> 1);
        const int slot = d * 8 + (kseg ^ (d & 7));
        vf[ks][dt] = *(const half4*)(&Vs[cur][slot * 8 + (quad & 1) * 4]);
      }
    }
    // ---- online softmax (lane owns q = i2*16+l15; keys split over quads)
    half4 pb[2][4];
    float alpha[2];
#pragma unroll
    for (int i2 = 0; i2 < 2; i2++) {
      float mx = sacc[i2][0][0];
#pragma unroll
      for (int t4 = 0; t4 < 4; t4++)
#pragma unroll
        for (int r = 0; r < 4; r++) mx = fmaxf(mx, sacc[i2][t4][r]);
      mx = fmaxf(mx, __shfl_xor(mx, 16, 64));
      mx = fmaxf(mx, __shfl_xor(mx, 32, 64));
      const float mnew = fmaxf(mrun[i2], mx);
      const float a = exp2f(mrun[i2] - mnew);
      float ls = 0.0f;
#pragma unroll
      for (int t4 = 0; t4 < 4; t4++) {
#pragma unroll
        for (int r = 0; r < 4; r++) {
          const float p = exp2f(sacc[i2][t4][r] - mnew);
          sacc[i2][t4][r] = p;
          ls += p;
        }
      }
      ls += __shfl_xor(ls, 16, 64);
      ls += __shfl_xor(ls, 32, 64);
      lrun[i2] = lrun[i2] * a + ls;
      mrun[i2] = mnew;
      alpha[i2] = a;
#pragma unroll
      for (int t4 = 0; t4 < 4; t4++) {
        half4 ph;
        ph[0] = (_Float16)sacc[i2][t4][0];
        ph[1] = (_Float16)sacc[i2][t4][1];
        ph[2] = (_Float16)sacc[i2][t4][2];
        ph[3] = (_Float16)sacc[i2][t4][3];
        pb[i2][t4] = ph;
      }
    }
#pragma unroll
    for (int dt = 0; dt < 4; dt++)
#pragma unroll
      for (int i2 = 0; i2 < 2; i2++) co[dt][i2] *= alpha[i2];
    // ---- O^T += V^T P^T  (both operands in registers)
#pragma unroll
    for (int ks = 0; ks < 4; ks++)
#pragma unroll
      for (int dt = 0; dt < 4; dt++)
#pragma unroll
        for (int i2 = 0; i2 < 2; i2++)
          co[dt][i2] = __builtin_amdgcn_mfma_f32_16x16x16f16(vf[ks][dt], pb[i2][ks],
                                                             co[dt][i2], 0, 0, 0);
    __syncthreads();  // drains stage loads; separates buffer reuse
  }

  // ---- epilogue: ctxr[b*2048 + q][h*64 + d] = co^T / l
#pragma unroll
  for (int i2 = 0; i2 < 2; i2++) {
    const float inv = 1.0f / lrun[i2];
    const int srow = qrow0 + i2 * 16 + l15;
#pragma unroll
    for (int dt = 0; dt < 4; dt++) {
#pragma unroll
      for (int r = 0; r < 4; r++) {
        const int col = h * 64 + dt * 16 + quad * 4 + r;
        ctxr[(size_t)(b * 2048 + srow) * 1024 + col] = bf16rne(co[dt][i2][r] * inv);
      }
    }
  }
}

// ---------------------------------------------------------------------------
extern "C" void kernel_launch(void* const* d_in, const int* in_sizes, int n_in,
                              void* d_out, int out_size, void* d_ws, size_t ws_size,
                              hipStream_t stream) {
  const float* Q = (const float*)d_in[0];
  const float* K = (const float*)d_in[1];
  const float* V = (const float*)d_in[2];
  const float* WQ = (const float*)d_in[3];
  const float* WK = (const float*)d_in[4];
  const float* WV = (const float*)d_in[5];
  const float* Wfc = (const float*)d_in[6];
  float* out = (float*)d_out;

  unsigned short* ws = (unsigned short*)d_ws;
  // ws layout (ushort units):
  //   Xb   @ 0         : 3*8388608  (bf16 Q,K,V)      [dead after projections]
  //   ctxr @ 0         : 8388608    (bf16 ctx)        [overlays Xb]
  //   Vt   @ 8388608   : 8388608    (f16 V^T)         [overlays Xb]
  //   Wt   @ 25165824  : 4*1048576  (bf16 W^T: q,k,v,fc)
  //   lin  @ 29360128  : 3*8388608  (bf16 projections)
  unsigned short* Xb = ws;
  unsigned short* ctxr = ws;
  unsigned short* Vt = ws + 8388608;
  unsigned short* Wt = ws + 25165824;
  unsigned short* lin = ws + 29360128;

  convert_x_kernel<<<dim3(4096, 3), 256, 0, stream>>>(Q, K, V, Xb);
  convert_w_kernel<<<dim3(32, 32, 4), 256, 0, stream>>>(WQ, WK, WV, Wfc, Wt);
  const float qscale = 0.125f * 1.4426950408889634f;  // 1/sqrt(dk) * log2(e)
  gemm_bt_kernel<<<dim3(64, 8, 3), 256, 0, stream>>>(Xb, Wt, lin, nullptr, qscale);
  vtrans_kernel<<<dim3(16, 64), 256, 0, stream>>>(lin + 16777216, Vt);
  attn_kernel<<<dim3(64, 16), 256, 0, stream>>>(lin, (const _Float16*)Vt, ctxr);
  gemm_bt_kernel<<<dim3(64, 8, 1), 256, 0, stream>>>(ctxr, Wt + 3 * 1048576, nullptr,
                                                     out, 1.0f);
}